// Round 11
// baseline (82.864 us; speedup 1.0000x reference)
//
#include <hip/hip_runtime.h>

#define HW   16384
#define WID  128
#define HEI  128
#define CIN  64
#define OCH  64

typedef __attribute__((ext_vector_type(8))) short bf16x8;
typedef __attribute__((ext_vector_type(4))) float f32x4;
typedef __attribute__((ext_vector_type(4))) int   i32x4;

__device__ __forceinline__ unsigned short f2bf(float f) {
    unsigned u = __float_as_uint(f);
    u += 0x7FFF + ((u >> 16) & 1);          // RNE
    return (unsigned short)(u >> 16);
}
__device__ __forceinline__ float bf2f(short s) {
    return __uint_as_float(((unsigned)(unsigned short)s) << 16);
}

// ---------------- kernel P: x transpose + weight pack + stats zero ---------
// blocks 0..255:   x NCHW f32 -> NHWC bf16 (block 0 also zeroes stats)
// blocks 256..471: pack w_dcn (36864) and w_off (18432) into B-fragment order
__global__ __launch_bounds__(256) void kprep(const float* __restrict__ x,
                                             const float* __restrict__ wdcn,
                                             const float* __restrict__ woff,
                                             unsigned short* __restrict__ xt,
                                             unsigned short* __restrict__ wpack,
                                             unsigned short* __restrict__ woffpack,
                                             float* __restrict__ stats) {
    int blk = blockIdx.x;
    if (blk < 256) {
        if (blk == 0 && threadIdx.x < 128) stats[threadIdx.x] = 0.f;
        int gp = blk * 256 + threadIdx.x;      // 0..65535 = (b, hw)
        int b = gp >> 14;
        int hw = gp & (HW - 1);
        const float* xb = x + (size_t)b * CIN * HW + hw;
        unsigned short* o = xt + ((size_t)gp << 6);
#pragma unroll
        for (int c8 = 0; c8 < 8; c8++) {
            bf16x8 v;
#pragma unroll
            for (int j = 0; j < 8; j++)
                v[j] = (short)f2bf(xb[(size_t)(c8 * 8 + j) * HW]);
            *(bf16x8*)(o + c8 * 8) = v;
        }
    } else {
        int t = (blk - 256) * 256 + threadIdx.x;   // 0..55295
        if (t < 36864) {
            int j  = t & 7;
            int l  = (t >> 3) & 63;
            int nt = (t >> 9) & 3;
            int s  = t >> 11;                      // 0..17
            int k  = s * 32 + (l >> 4) * 8 + j;
            int o  = nt * 16 + (l & 15);
            int tap = k >> 6, c = k & 63;
            wpack[t] = f2bf(wdcn[o * 576 + c * 9 + tap]);
        } else {
            int u  = t - 36864;                    // 0..18431
            int j  = u & 7;
            int l  = (u >> 3) & 63;
            int nt = (u >> 9) & 1;
            int s  = u >> 10;                      // 0..17
            int k  = s * 32 + (l >> 4) * 8 + j;
            int o  = nt * 16 + (l & 15);
            int tap = k >> 6, c = k & 63;
            float v = (o < 18) ? woff[o * 576 + c * 9 + tap] : 0.f;
            woffpack[u] = f2bf(v);
        }
    }
}

// ---------------- kernel B: offset conv + deformable sample + MFMA + stats -
// block = 4 waves, 32 consecutive-w pixels.
// LDS: patch bf16 [32 px][576 k] pitch 1152B, XOR-swizzled by (px&7)<<4 (0..36863)
//      tapinfo [288][8] u32 (36864..46079)
//      offLds f32 [32 px][18 oc]   (46080..48383)
__global__ __launch_bounds__(256, 3) void kdcn(const unsigned short* __restrict__ xt,
                                               const unsigned short* __restrict__ wpack,
                                               const unsigned short* __restrict__ woffpack,
                                               const float* __restrict__ boff,
                                               const float* __restrict__ bdcn,
                                               float* __restrict__ conv,
                                               float* __restrict__ stats) {
    __shared__ __align__(16) unsigned char smem[48384];

    int tid = threadIdx.x;
    int lane = tid & 63, wave = tid >> 6;
    int lr = lane & 15, hi = lane >> 4;

    int pixg = blockIdx.x * 32;
    int b = pixg >> 14;                 // uniform
    int hwb = pixg & (HW - 1);
    int h = hwb >> 7;                   // uniform (32 | 128)
    int w0 = hwb & (WID - 1);

    // ---- phase 0: stage REGULAR 3x3 patch (zero-padded) into LDS ----------
    {
        int g = lane >> 3, sub = lane & 7;
        int px = wave * 8 + g;
        int w = w0 + px;
        const unsigned char* xtb =
            (const unsigned char*)xt + (((size_t)b * HW) << 7) + sub * 16;
        unsigned char* prow = smem + px * 1152;
        unsigned swz = (unsigned)((px & 7) << 4);
#pragma unroll
        for (int tap = 0; tap < 9; tap++) {
            int sy = h + tap / 3 - 1;
            int sx = w + tap % 3 - 1;
            bool ok = ((unsigned)sy < HEI) && ((unsigned)sx < WID);
            bf16x8 v = {0, 0, 0, 0, 0, 0, 0, 0};
            if (ok) v = *(const bf16x8*)(xtb + ((sy * WID + sx) << 7));
            *(bf16x8*)(prow + ((unsigned)(tap * 128 + sub * 16) ^ swz)) = v;
        }
    }
    __syncthreads();

    // ---- phase 0b: offset conv via MFMA; D[32 px][18 oc] -> offLds --------
    {
        int mw = wave & 1, nw = wave >> 1;
        int oc = nw * 16 + lr;
        float ob = (oc < 18) ? boff[oc] : 0.f;
        f32x4 oacc = {ob, ob, ob, ob};
        unsigned swzr = (unsigned)((lr & 7) << 4);
        const unsigned short* wop = woffpack + (size_t)(nw * 64 + lane) * 8;
        int arow = (mw * 16 + lr) * 1152;
#pragma unroll
        for (int s = 0; s < 18; s++) {
            unsigned inblk = (unsigned)((s >> 1) * 128)
                           + (((unsigned)((s & 1) * 64 + hi * 16)) ^ swzr);
            bf16x8 a  = *(const bf16x8*)(smem + arow + inblk);
            bf16x8 wf = *(const bf16x8*)(wop + (size_t)s * 1024);
            oacc = __builtin_amdgcn_mfma_f32_16x16x32_bf16(a, wf, oacc, 0, 0, 0);
        }
        float* offLds = (float*)(smem + 46080);
        if (oc < 18) {
#pragma unroll
            for (int r = 0; r < 4; r++)
                offLds[(mw * 16 + hi * 4 + r) * 18 + oc] = oacc[r];
        }
    }
    __syncthreads();

    // ---- phase A: per-(px,tap) NHWC byte offsets + validity-folded weights
    int* ti = (int*)(smem + 36864);
    {
        const float* offLds = (const float*)(smem + 46080);
        for (int item = tid; item < 288; item += 256) {
            int ppx = item / 9, tap = item - ppx * 9;
            float dy = offLds[ppx * 18 + tap * 2];
            float dx = offLds[ppx * 18 + tap * 2 + 1];
            float py  = dy + (float)(h + tap / 3 - 1);
            float pxf = dx + (float)(w0 + ppx + tap % 3 - 1);
            float y0f = floorf(py), x0f = floorf(pxf);
            float wy = py - y0f, wx = pxf - x0f;
            int y0 = (int)y0f, x0 = (int)x0f;
            float wy0 = ((unsigned)y0       < HEI) ? 1.f - wy : 0.f;
            float wy1 = ((unsigned)(y0 + 1) < HEI) ? wy       : 0.f;
            float wx0 = ((unsigned)x0       < WID) ? 1.f - wx : 0.f;
            float wx1 = ((unsigned)(x0 + 1) < WID) ? wx       : 0.f;
            int yc0 = min(max(y0, 0),     HEI - 1) * WID;
            int yc1 = min(max(y0 + 1, 0), HEI - 1) * WID;
            int xc0 = min(max(x0, 0),     WID - 1);
            int xc1 = min(max(x0 + 1, 0), WID - 1);
            int* t8 = ti + item * 8;
            t8[0] = (yc0 + xc0) << 7;      // byte offset into NHWC bf16
            t8[1] = (yc0 + xc1) << 7;
            t8[2] = (yc1 + xc0) << 7;
            t8[3] = (yc1 + xc1) << 7;
            float* f8 = (float*)t8;
            f8[4] = wy0 * wx0; f8[5] = wy0 * wx1;
            f8[6] = wy1 * wx0; f8[7] = wy1 * wx1;
        }
    }
    __syncthreads();

    // ---- B fragments + bias (o = wave*16 + lr)
    bf16x8 bfrag[18];
    const unsigned short* wp = wpack + (size_t)(wave * 64 + lane) * 8;
#pragma unroll
    for (int s = 0; s < 18; s++)
        bfrag[s] = *(const bf16x8*)(wp + (size_t)s * 2048);
    float bias = bdcn[wave * 16 + lr];

    // ---- phase B: 8 lanes per px; each lane owns 8 channels, loops 9 taps
    {
        int g = lane >> 3, sub = lane & 7;
        int px = wave * 8 + g;
        const unsigned char* xtb =
            (const unsigned char*)xt + (((size_t)b * HW) << 7) + sub * 16;
        unsigned char* prow = smem + px * 1152;
        unsigned swz = (unsigned)((px & 7) << 4);
        const int* tbase = ti + px * 72;
#pragma unroll
        for (int tap = 0; tap < 9; tap++) {
            i32x4 t4 = *(const i32x4*)(tbase + tap * 8);
            f32x4 w4 = *(const f32x4*)(tbase + tap * 8 + 4);
            bf16x8 c00 = *(const bf16x8*)(xtb + t4[0]);
            bf16x8 c01 = *(const bf16x8*)(xtb + t4[1]);
            bf16x8 c10 = *(const bf16x8*)(xtb + t4[2]);
            bf16x8 c11 = *(const bf16x8*)(xtb + t4[3]);
            bf16x8 v;
#pragma unroll
            for (int j = 0; j < 8; j++) {
                float sv = w4[0] * bf2f(c00[j]) + w4[1] * bf2f(c01[j])
                         + w4[2] * bf2f(c10[j]) + w4[3] * bf2f(c11[j]);
                v[j] = (short)f2bf(sv);
            }
            *(bf16x8*)(prow + ((unsigned)(tap * 128 + sub * 16) ^ swz)) = v;
        }
    }
    __syncthreads();

    // ---- main MFMA: D[32 px][64 o], wave owns o-tile = wave
    f32x4 acc0 = {bias, bias, bias, bias};
    f32x4 acc1 = acc0;
    unsigned swzr = (unsigned)((lr & 7) << 4);
#pragma unroll
    for (int s = 0; s < 18; s++) {
        unsigned inblk = (unsigned)((s >> 1) * 128)
                       + (((unsigned)((s & 1) * 64 + hi * 16)) ^ swzr);
        bf16x8 a0 = *(const bf16x8*)(smem + lr * 1152 + inblk);
        bf16x8 a1 = *(const bf16x8*)(smem + (16 + lr) * 1152 + inblk);
        acc0 = __builtin_amdgcn_mfma_f32_16x16x32_bf16(a0, bfrag[s], acc0, 0, 0, 0);
        acc1 = __builtin_amdgcn_mfma_f32_16x16x32_bf16(a1, bfrag[s], acc1, 0, 0, 0);
    }

    // ---- BN partial stats: channel o = wave*16+lr over this block's 32 px -
    {
        float s  = acc0[0] + acc0[1] + acc0[2] + acc0[3]
                 + acc1[0] + acc1[1] + acc1[2] + acc1[3];
        float s2 = acc0[0]*acc0[0] + acc0[1]*acc0[1] + acc0[2]*acc0[2] + acc0[3]*acc0[3]
                 + acc1[0]*acc1[0] + acc1[1]*acc1[1] + acc1[2]*acc1[2] + acc1[3]*acc1[3];
        s  += __shfl_xor(s, 16);  s2 += __shfl_xor(s2, 16);
        s  += __shfl_xor(s, 32);  s2 += __shfl_xor(s2, 32);
        if (hi == 0) {
            atomicAdd(&stats[wave * 16 + lr], s);
            atomicAdd(&stats[64 + wave * 16 + lr], s2);
        }
    }
    __syncthreads();

    // ---- epilogue: transpose via LDS, coalesced float4 stores
    float* ldsC = (float*)smem;                    // [64][33]
    {
        int o = wave * 16 + lr;
        int pxb = hi * 4;
#pragma unroll
        for (int r = 0; r < 4; r++) {
            ldsC[o * 33 + pxb + r]      = acc0[r];
            ldsC[o * 33 + 16 + pxb + r] = acc1[r];
        }
    }
    __syncthreads();
    {
        int px4 = (tid & 7) * 4;
#pragma unroll
        for (int pass = 0; pass < 2; pass++) {
            int oo = (tid >> 3) + pass * 32;
            float4 v;
            v.x = ldsC[oo * 33 + px4];
            v.y = ldsC[oo * 33 + px4 + 1];
            v.z = ldsC[oo * 33 + px4 + 2];
            v.w = ldsC[oo * 33 + px4 + 3];
            *(float4*)(conv + ((size_t)b * OCH + oo) * HW + hwb + px4) = v;
        }
    }
}

// ---------------- kernel D: finalize stats + normalize + relu (in-place) ---
__global__ __launch_bounds__(256) void kapply(float* __restrict__ conv,
                                              const float* __restrict__ stats,
                                              const float* __restrict__ gamma,
                                              const float* __restrict__ beta) {
    int t = blockIdx.x * 256 + threadIdx.x;   // < 1048576 float4s
    int c = (t >> 12) & 63;
    float mean = stats[c] * (1.f / 65536.f);
    float var  = stats[64 + c] * (1.f / 65536.f) - mean * mean;
    float rstd = rsqrtf(var + 1e-5f);
    float sc = rstd * gamma[c];
    float sh = beta[c] - mean * sc;
    float4 v = ((float4*)conv)[t];
    float4 r;
    r.x = fmaxf(v.x * sc + sh, 0.f);
    r.y = fmaxf(v.y * sc + sh, 0.f);
    r.z = fmaxf(v.z * sc + sh, 0.f);
    r.w = fmaxf(v.w * sc + sh, 0.f);
    ((float4*)conv)[t] = r;
}

// ---------------- launch ---------------------------------------------------
extern "C" void kernel_launch(void* const* d_in, const int* in_sizes, int n_in,
                              void* d_out, int out_size, void* d_ws, size_t ws_size,
                              hipStream_t stream) {
    const float* x     = (const float*)d_in[0];
    const float* woff  = (const float*)d_in[1];
    const float* boff  = (const float*)d_in[2];
    const float* wdcn  = (const float*)d_in[3];
    const float* bdcn  = (const float*)d_in[4];
    const float* gamma = (const float*)d_in[5];
    const float* beta  = (const float*)d_in[6];
    float* out = (float*)d_out;   // also holds pre-BN conv result

    // workspace layout (bytes): xt 8 MB | wpack 72 KB | woffpack 36 KB | stats
    unsigned char* ws = (unsigned char*)d_ws;
    unsigned short* xt       = (unsigned short*)ws;            // 4,194,304 ush
    unsigned short* wpack    = (unsigned short*)(ws + 8388608);//    36,864 ush
    unsigned short* woffpack = (unsigned short*)(ws + 8462336);//    18,432 ush
    float*          stats    = (float*)(ws + 8499200);         //       128 f
    // total ~8.5 MB

    hipLaunchKernelGGL(kprep,  dim3(472),  dim3(256), 0, stream,
                       x, wdcn, woff, xt, wpack, woffpack, stats);
    hipLaunchKernelGGL(kdcn,   dim3(2048), dim3(256), 0, stream,
                       xt, wpack, woffpack, boff, bdcn, out, stats);
    hipLaunchKernelGGL(kapply, dim3(4096), dim3(256), 0, stream,
                       out, stats, gamma, beta);
}

// Round 12
// 56.524 us; speedup vs baseline: 1.4660x; 1.4660x over previous
//
#include <hip/hip_runtime.h>

#define HW   16384
#define WID  128
#define HEI  128
#define CIN  64
#define OCH  64

typedef __attribute__((ext_vector_type(8))) short bf16x8;
typedef __attribute__((ext_vector_type(4))) float f32x4;
typedef __attribute__((ext_vector_type(4))) int   i32x4;

__device__ __forceinline__ unsigned short f2bf(float f) {
    unsigned u = __float_as_uint(f);
    u += 0x7FFF + ((u >> 16) & 1);          // RNE
    return (unsigned short)(u >> 16);
}
__device__ __forceinline__ float bf2f(short s) {
    return __uint_as_float(((unsigned)(unsigned short)s) << 16);
}

// ---------------- kernel P: x transpose + weight pack ----------------------
// blocks 0..255:   x NCHW f32 -> NHWC bf16
// blocks 256..471: pack w_dcn (36864) and w_off (18432) into B-fragment order
__global__ __launch_bounds__(256) void kprep(const float* __restrict__ x,
                                             const float* __restrict__ wdcn,
                                             const float* __restrict__ woff,
                                             unsigned short* __restrict__ xt,
                                             unsigned short* __restrict__ wpack,
                                             unsigned short* __restrict__ woffpack) {
    int blk = blockIdx.x;
    if (blk < 256) {
        int gp = blk * 256 + threadIdx.x;      // 0..65535 = (b, hw)
        int b = gp >> 14;
        int hw = gp & (HW - 1);
        const float* xb = x + (size_t)b * CIN * HW + hw;
        unsigned short* o = xt + ((size_t)gp << 6);
#pragma unroll
        for (int c8 = 0; c8 < 8; c8++) {
            bf16x8 v;
#pragma unroll
            for (int j = 0; j < 8; j++)
                v[j] = (short)f2bf(xb[(size_t)(c8 * 8 + j) * HW]);
            *(bf16x8*)(o + c8 * 8) = v;
        }
    } else {
        int t = (blk - 256) * 256 + threadIdx.x;   // 0..55295
        if (t < 36864) {
            int j  = t & 7;
            int l  = (t >> 3) & 63;
            int nt = (t >> 9) & 3;
            int s  = t >> 11;                      // 0..17
            int k  = s * 32 + (l >> 4) * 8 + j;
            int o  = nt * 16 + (l & 15);
            int tap = k >> 6, c = k & 63;
            wpack[t] = f2bf(wdcn[o * 576 + c * 9 + tap]);
        } else {
            int u  = t - 36864;                    // 0..18431
            int j  = u & 7;
            int l  = (u >> 3) & 63;
            int nt = (u >> 9) & 1;
            int s  = u >> 10;                      // 0..17
            int k  = s * 32 + (l >> 4) * 8 + j;
            int o  = nt * 16 + (l & 15);
            int tap = k >> 6, c = k & 63;
            float v = (o < 18) ? woff[o * 576 + c * 9 + tap] : 0.f;
            woffpack[u] = f2bf(v);
        }
    }
}

// ---------------- kernel B: offset conv + deformable sample + MFMA ---------
// block = 4 waves, 32 consecutive-w pixels.
// LDS: patch bf16 [32 px][576 k] pitch 1152B, XOR-swizzled by (px&7)<<4 (0..36863)
//      tapinfo [288][8] u32 (36864..46079)
//      offLds f32 [32 px][18 oc]   (46080..48383)
// BN partials: plain stores to part[chan][block] at kernel end (no atomics,
// no barrier after them -> no contended vmcnt drain).
__global__ __launch_bounds__(256, 3) void kdcn(const unsigned short* __restrict__ xt,
                                               const unsigned short* __restrict__ wpack,
                                               const unsigned short* __restrict__ woffpack,
                                               const float* __restrict__ boff,
                                               const float* __restrict__ bdcn,
                                               float* __restrict__ conv,
                                               float* __restrict__ part) {
    __shared__ __align__(16) unsigned char smem[48384];

    int tid = threadIdx.x;
    int lane = tid & 63, wave = tid >> 6;
    int lr = lane & 15, hi = lane >> 4;

    int pixg = blockIdx.x * 32;
    int b = pixg >> 14;                 // uniform
    int hwb = pixg & (HW - 1);
    int h = hwb >> 7;                   // uniform (32 | 128)
    int w0 = hwb & (WID - 1);

    // ---- phase 0: stage REGULAR 3x3 patch (zero-padded) into LDS ----------
    {
        int g = lane >> 3, sub = lane & 7;
        int px = wave * 8 + g;
        int w = w0 + px;
        const unsigned char* xtb =
            (const unsigned char*)xt + (((size_t)b * HW) << 7) + sub * 16;
        unsigned char* prow = smem + px * 1152;
        unsigned swz = (unsigned)((px & 7) << 4);
#pragma unroll
        for (int tap = 0; tap < 9; tap++) {
            int sy = h + tap / 3 - 1;
            int sx = w + tap % 3 - 1;
            bool ok = ((unsigned)sy < HEI) && ((unsigned)sx < WID);
            bf16x8 v = {0, 0, 0, 0, 0, 0, 0, 0};
            if (ok) v = *(const bf16x8*)(xtb + ((sy * WID + sx) << 7));
            *(bf16x8*)(prow + ((unsigned)(tap * 128 + sub * 16) ^ swz)) = v;
        }
    }
    __syncthreads();

    // ---- phase 0b: offset conv via MFMA; D[32 px][18 oc] -> offLds --------
    {
        int mw = wave & 1, nw = wave >> 1;
        int oc = nw * 16 + lr;
        float ob = (oc < 18) ? boff[oc] : 0.f;
        f32x4 oacc = {ob, ob, ob, ob};
        unsigned swzr = (unsigned)((lr & 7) << 4);
        const unsigned short* wop = woffpack + (size_t)(nw * 64 + lane) * 8;
        int arow = (mw * 16 + lr) * 1152;
#pragma unroll
        for (int s = 0; s < 18; s++) {
            unsigned inblk = (unsigned)((s >> 1) * 128)
                           + (((unsigned)((s & 1) * 64 + hi * 16)) ^ swzr);
            bf16x8 a  = *(const bf16x8*)(smem + arow + inblk);
            bf16x8 wf = *(const bf16x8*)(wop + (size_t)s * 1024);
            oacc = __builtin_amdgcn_mfma_f32_16x16x32_bf16(a, wf, oacc, 0, 0, 0);
        }
        float* offLds = (float*)(smem + 46080);
        if (oc < 18) {
#pragma unroll
            for (int r = 0; r < 4; r++)
                offLds[(mw * 16 + hi * 4 + r) * 18 + oc] = oacc[r];
        }
    }
    __syncthreads();

    // ---- phase A: per-(px,tap) NHWC byte offsets + validity-folded weights
    int* ti = (int*)(smem + 36864);
    {
        const float* offLds = (const float*)(smem + 46080);
        for (int item = tid; item < 288; item += 256) {
            int ppx = item / 9, tap = item - ppx * 9;
            float dy = offLds[ppx * 18 + tap * 2];
            float dx = offLds[ppx * 18 + tap * 2 + 1];
            float py  = dy + (float)(h + tap / 3 - 1);
            float pxf = dx + (float)(w0 + ppx + tap % 3 - 1);
            float y0f = floorf(py), x0f = floorf(pxf);
            float wy = py - y0f, wx = pxf - x0f;
            int y0 = (int)y0f, x0 = (int)x0f;
            float wy0 = ((unsigned)y0       < HEI) ? 1.f - wy : 0.f;
            float wy1 = ((unsigned)(y0 + 1) < HEI) ? wy       : 0.f;
            float wx0 = ((unsigned)x0       < WID) ? 1.f - wx : 0.f;
            float wx1 = ((unsigned)(x0 + 1) < WID) ? wx       : 0.f;
            int yc0 = min(max(y0, 0),     HEI - 1) * WID;
            int yc1 = min(max(y0 + 1, 0), HEI - 1) * WID;
            int xc0 = min(max(x0, 0),     WID - 1);
            int xc1 = min(max(x0 + 1, 0), WID - 1);
            int* t8 = ti + item * 8;
            t8[0] = (yc0 + xc0) << 7;      // byte offset into NHWC bf16
            t8[1] = (yc0 + xc1) << 7;
            t8[2] = (yc1 + xc0) << 7;
            t8[3] = (yc1 + xc1) << 7;
            float* f8 = (float*)t8;
            f8[4] = wy0 * wx0; f8[5] = wy0 * wx1;
            f8[6] = wy1 * wx0; f8[7] = wy1 * wx1;
        }
    }
    __syncthreads();

    // ---- B fragments + bias (o = wave*16 + lr)
    bf16x8 bfrag[18];
    const unsigned short* wp = wpack + (size_t)(wave * 64 + lane) * 8;
#pragma unroll
    for (int s = 0; s < 18; s++)
        bfrag[s] = *(const bf16x8*)(wp + (size_t)s * 2048);
    float bias = bdcn[wave * 16 + lr];

    // ---- phase B: 8 lanes per px; each lane owns 8 channels, loops 9 taps
    {
        int g = lane >> 3, sub = lane & 7;
        int px = wave * 8 + g;
        const unsigned char* xtb =
            (const unsigned char*)xt + (((size_t)b * HW) << 7) + sub * 16;
        unsigned char* prow = smem + px * 1152;
        unsigned swz = (unsigned)((px & 7) << 4);
        const int* tbase = ti + px * 72;
#pragma unroll
        for (int tap = 0; tap < 9; tap++) {
            i32x4 t4 = *(const i32x4*)(tbase + tap * 8);
            f32x4 w4 = *(const f32x4*)(tbase + tap * 8 + 4);
            bf16x8 c00 = *(const bf16x8*)(xtb + t4[0]);
            bf16x8 c01 = *(const bf16x8*)(xtb + t4[1]);
            bf16x8 c10 = *(const bf16x8*)(xtb + t4[2]);
            bf16x8 c11 = *(const bf16x8*)(xtb + t4[3]);
            bf16x8 v;
#pragma unroll
            for (int j = 0; j < 8; j++) {
                float sv = w4[0] * bf2f(c00[j]) + w4[1] * bf2f(c01[j])
                         + w4[2] * bf2f(c10[j]) + w4[3] * bf2f(c11[j]);
                v[j] = (short)f2bf(sv);
            }
            *(bf16x8*)(prow + ((unsigned)(tap * 128 + sub * 16) ^ swz)) = v;
        }
    }
    __syncthreads();

    // ---- main MFMA: D[32 px][64 o], wave owns o-tile = wave
    f32x4 acc0 = {bias, bias, bias, bias};
    f32x4 acc1 = acc0;
    unsigned swzr = (unsigned)((lr & 7) << 4);
#pragma unroll
    for (int s = 0; s < 18; s++) {
        unsigned inblk = (unsigned)((s >> 1) * 128)
                       + (((unsigned)((s & 1) * 64 + hi * 16)) ^ swzr);
        bf16x8 a0 = *(const bf16x8*)(smem + lr * 1152 + inblk);
        bf16x8 a1 = *(const bf16x8*)(smem + (16 + lr) * 1152 + inblk);
        acc0 = __builtin_amdgcn_mfma_f32_16x16x32_bf16(a0, bfrag[s], acc0, 0, 0, 0);
        acc1 = __builtin_amdgcn_mfma_f32_16x16x32_bf16(a1, bfrag[s], acc1, 0, 0, 0);
    }
    __syncthreads();

    // ---- epilogue: transpose via LDS, coalesced float4 stores
    float* ldsC = (float*)smem;                    // [64][33]
    {
        int o = wave * 16 + lr;
        int pxb = hi * 4;
#pragma unroll
        for (int r = 0; r < 4; r++) {
            ldsC[o * 33 + pxb + r]      = acc0[r];
            ldsC[o * 33 + 16 + pxb + r] = acc1[r];
        }
    }
    __syncthreads();
    {
        int px4 = (tid & 7) * 4;
#pragma unroll
        for (int pass = 0; pass < 2; pass++) {
            int oo = (tid >> 3) + pass * 32;
            float4 v;
            v.x = ldsC[oo * 33 + px4];
            v.y = ldsC[oo * 33 + px4 + 1];
            v.z = ldsC[oo * 33 + px4 + 2];
            v.w = ldsC[oo * 33 + px4 + 3];
            *(float4*)(conv + ((size_t)b * OCH + oo) * HW + hwb + px4) = v;
        }
    }

    // ---- BN partials (AFTER epilogue; no barrier follows, no contention) --
    {
        float s  = acc0[0] + acc0[1] + acc0[2] + acc0[3]
                 + acc1[0] + acc1[1] + acc1[2] + acc1[3];
        float s2 = acc0[0]*acc0[0] + acc0[1]*acc0[1] + acc0[2]*acc0[2] + acc0[3]*acc0[3]
                 + acc1[0]*acc1[0] + acc1[1]*acc1[1] + acc1[2]*acc1[2] + acc1[3]*acc1[3];
        s  += __shfl_xor(s, 16);  s2 += __shfl_xor(s2, 16);
        s  += __shfl_xor(s, 32);  s2 += __shfl_xor(s2, 32);
        if (hi == 0) {
            int c = wave * 16 + lr;
            part[(size_t)c * 2048 + blockIdx.x]        = s;
            part[(size_t)(64 + c) * 2048 + blockIdx.x] = s2;
        }
    }
}

// ---------------- kernel R: reduce partials -> stats[128] ------------------
__global__ __launch_bounds__(256) void kred(const float* __restrict__ part,
                                            float* __restrict__ stats) {
    int row = blockIdx.x;                 // 0..127
    int tid = threadIdx.x;
    const float* p = part + (size_t)row * 2048;
    float s = 0.f;
#pragma unroll
    for (int i = 0; i < 8; i++) s += p[tid + i * 256];
#pragma unroll
    for (int d = 1; d < 64; d <<= 1) s += __shfl_xor(s, d);
    __shared__ float red[4];
    if ((tid & 63) == 0) red[tid >> 6] = s;
    __syncthreads();
    if (tid == 0) stats[row] = red[0] + red[1] + red[2] + red[3];
}

// ---------------- kernel D: finalize stats + normalize + relu (in-place) ---
__global__ __launch_bounds__(256) void kapply(float* __restrict__ conv,
                                              const float* __restrict__ stats,
                                              const float* __restrict__ gamma,
                                              const float* __restrict__ beta) {
    int t = blockIdx.x * 256 + threadIdx.x;   // < 1048576 float4s
    int c = (t >> 12) & 63;
    float mean = stats[c] * (1.f / 65536.f);
    float var  = stats[64 + c] * (1.f / 65536.f) - mean * mean;
    float rstd = rsqrtf(var + 1e-5f);
    float sc = rstd * gamma[c];
    float sh = beta[c] - mean * sc;
    float4 v = ((float4*)conv)[t];
    float4 r;
    r.x = fmaxf(v.x * sc + sh, 0.f);
    r.y = fmaxf(v.y * sc + sh, 0.f);
    r.z = fmaxf(v.z * sc + sh, 0.f);
    r.w = fmaxf(v.w * sc + sh, 0.f);
    ((float4*)conv)[t] = r;
}

// ---------------- launch ---------------------------------------------------
extern "C" void kernel_launch(void* const* d_in, const int* in_sizes, int n_in,
                              void* d_out, int out_size, void* d_ws, size_t ws_size,
                              hipStream_t stream) {
    const float* x     = (const float*)d_in[0];
    const float* woff  = (const float*)d_in[1];
    const float* boff  = (const float*)d_in[2];
    const float* wdcn  = (const float*)d_in[3];
    const float* bdcn  = (const float*)d_in[4];
    const float* gamma = (const float*)d_in[5];
    const float* beta  = (const float*)d_in[6];
    float* out = (float*)d_out;   // also holds pre-BN conv result

    // ws layout (bytes): xt 8MB | wpack 72KB | woffpack 36KB | part 1MB | stats
    unsigned char* ws = (unsigned char*)d_ws;
    unsigned short* xt       = (unsigned short*)ws;            // 4,194,304 ush
    unsigned short* wpack    = (unsigned short*)(ws + 8388608);//    36,864 ush
    unsigned short* woffpack = (unsigned short*)(ws + 8462336);//    18,432 ush
    float*          part     = (float*)(ws + 8499200);         //   262,144 f
    float*          stats    = (float*)(ws + 9547776);         //       128 f
    // total ~9.55 MB

    hipLaunchKernelGGL(kprep,  dim3(472),  dim3(256), 0, stream,
                       x, wdcn, woff, xt, wpack, woffpack);
    hipLaunchKernelGGL(kdcn,   dim3(2048), dim3(256), 0, stream,
                       xt, wpack, woffpack, boff, bdcn, out, part);
    hipLaunchKernelGGL(kred,   dim3(128),  dim3(256), 0, stream, part, stats);
    hipLaunchKernelGGL(kapply, dim3(4096), dim3(256), 0, stream,
                       out, stats, gamma, beta);
}